// Round 1
// baseline (2089.078 us; speedup 1.0000x reference)
//
#include <hip/hip_runtime.h>
#include <hip/hip_bf16.h>

// Problem constants
#define CN1 262144
#define CN2 65536
#define CPREV 512
#define CSKIP 256
// feature width everywhere after the first MLPs = 256

using u16 = unsigned short;

__device__ __forceinline__ float toF(float v) { return v; }
__device__ __forceinline__ float toF(u16 u) { return __uint_as_float(((unsigned)u) << 16); }
__device__ __forceinline__ u16 f2bf(float f) {
    unsigned b = __float_as_uint(f);
    b += 0x7FFFu + ((b >> 16) & 1u);
    return (u16)(b >> 16);
}
__device__ __forceinline__ unsigned pack2(float lo, float hi) {
    return ((unsigned)f2bf(hi) << 16) | (unsigned)f2bf(lo);
}

// ---------------------------------------------------------------------------
// GEMM: C[M x 256] = A[M x K] @ W[K x 256] + bias, templated A/out dtypes.
// BM=128, BN=128, BK=16, 256 threads, 8x8 micro-tile per thread. fp32 VALU.
// ---------------------------------------------------------------------------
template<typename AT, typename OT>
__global__ __launch_bounds__(256) void gemm_bias_256(
    const AT* __restrict__ A, const float* __restrict__ W,
    const float* __restrict__ bias, OT* __restrict__ C,
    int M, int K)
{
    __shared__ float As[16][132];  // [k][m], pitch 132 (16B-aligned rows, spread banks)
    __shared__ float Wt[16][132];  // [k][n]
    const int bm = blockIdx.x * 128;
    const int bn = blockIdx.y * 128;
    const int tid = threadIdx.x;
    const int tx = tid & 15;
    const int ty = tid >> 4;

    float acc[8][8];
#pragma unroll
    for (int i = 0; i < 8; ++i)
#pragma unroll
        for (int j = 0; j < 8; ++j) acc[i][j] = 0.f;

    const int aj = tid & 15;   // k within tile
    const int am = tid >> 4;   // row group

    for (int k0 = 0; k0 < K; k0 += 16) {
#pragma unroll
        for (int t = 0; t < 8; ++t) {
            As[aj][am + t * 16] = toF(A[(size_t)(bm + am + t * 16) * K + (k0 + aj)]);
        }
#pragma unroll
        for (int t = 0; t < 8; ++t) {
            int e = t * 256 + tid;
            int j = e >> 7;
            int n = e & 127;
            Wt[j][n] = W[(size_t)(k0 + j) * 256 + bn + n];
        }
        __syncthreads();
#pragma unroll
        for (int kk = 0; kk < 16; ++kk) {
            float a[8], w[8];
#pragma unroll
            for (int i = 0; i < 8; ++i) a[i] = As[kk][ty * 8 + i];
#pragma unroll
            for (int j = 0; j < 8; ++j) w[j] = Wt[kk][tx * 8 + j];
#pragma unroll
            for (int i = 0; i < 8; ++i)
#pragma unroll
                for (int j = 0; j < 8; ++j)
                    acc[i][j] = fmaf(a[i], w[j], acc[i][j]);
        }
        __syncthreads();
    }

#pragma unroll
    for (int i = 0; i < 8; ++i) {
        size_t row = (size_t)bm + ty * 8 + i;
        size_t base = row * 256 + bn + tx * 8;
        float v[8];
#pragma unroll
        for (int j = 0; j < 8; ++j) v[j] = acc[i][j] + bias[bn + tx * 8 + j];
        if constexpr (sizeof(OT) == 4) {
            float4 v0 = make_float4(v[0], v[1], v[2], v[3]);
            float4 v1 = make_float4(v[4], v[5], v[6], v[7]);
            *reinterpret_cast<float4*>((float*)C + base) = v0;
            *reinterpret_cast<float4*>((float*)C + base + 4) = v1;
        } else {
            uint4 p;
            p.x = pack2(v[0], v[1]);
            p.y = pack2(v[2], v[3]);
            p.z = pack2(v[4], v[5]);
            p.w = pack2(v[6], v[7]);
            *reinterpret_cast<uint4*>((u16*)C + base) = p;
        }
    }
}

// ---------------------------------------------------------------------------
// Column stats: per-block partial sum / sumsq over a stripe of rows (width 256)
// ---------------------------------------------------------------------------
template<typename T>
__global__ __launch_bounds__(256) void colstats_partial(
    const T* __restrict__ X, int rpb, float* __restrict__ partial)
{
    int c = threadIdx.x;
    size_t r0 = (size_t)blockIdx.x * rpb;
    float s = 0.f, s2 = 0.f;
    for (int r = 0; r < rpb; ++r) {
        float v = toF(X[(r0 + r) * 256 + c]);
        s += v;
        s2 = fmaf(v, v, s2);
    }
    partial[(size_t)blockIdx.x * 512 + c] = s;
    partial[(size_t)blockIdx.x * 512 + 256 + c] = s2;
}

__global__ __launch_bounds__(256) void colstats_final(
    const float* __restrict__ partial, int nb, float invR,
    const float* __restrict__ g, const float* __restrict__ beta,
    float* __restrict__ ss)
{
    int c = threadIdx.x;
    float s = 0.f, s2 = 0.f;
    for (int b = 0; b < nb; ++b) {
        s += partial[(size_t)b * 512 + c];
        s2 += partial[(size_t)b * 512 + 256 + c];
    }
    float m = s * invR;
    float var = fmaf(-m, m, s2 * invR);
    float scale = g[c] * rsqrtf(var + 1e-5f);
    ss[c] = scale;
    ss[256 + c] = fmaf(-m, scale, beta[c]);
}

// ---------------------------------------------------------------------------
// x = relu( (sum_k w_k * y2[idx_k]) * sf + cf  +  skip * ssx + csx )
// skip read from x-buffer, result written in place. 4 rows/block, 64 lanes/row,
// 4 cols/lane (ushort4).
// ---------------------------------------------------------------------------
__global__ __launch_bounds__(256) void interp_relu(
    const u16* __restrict__ y2, u16* __restrict__ x,
    const float* __restrict__ dist, const int* __restrict__ idx,
    const float* __restrict__ ssf, const float* __restrict__ sss)
{
    int row = blockIdx.x * 4 + (threadIdx.x >> 6);
    int lane = threadIdx.x & 63;

    float d0 = dist[row * 3 + 0], d1 = dist[row * 3 + 1], d2 = dist[row * 3 + 2];
    float r0 = 1.f / (d0 + 1e-8f), r1 = 1.f / (d1 + 1e-8f), r2 = 1.f / (d2 + 1e-8f);
    float inv = 1.f / (r0 + r1 + r2);
    float w0 = r0 * inv, w1 = r1 * inv, w2 = r2 * inv;
    int i0 = idx[row * 3 + 0], i1 = idx[row * 3 + 1], i2 = idx[row * 3 + 2];

    ushort4 a0 = reinterpret_cast<const ushort4*>(y2 + (size_t)i0 * 256)[lane];
    ushort4 a1 = reinterpret_cast<const ushort4*>(y2 + (size_t)i1 * 256)[lane];
    ushort4 a2 = reinterpret_cast<const ushort4*>(y2 + (size_t)i2 * 256)[lane];
    ushort4 sk = reinterpret_cast<const ushort4*>(x + (size_t)row * 256)[lane];

    float4 sf = reinterpret_cast<const float4*>(ssf)[lane];
    float4 cf = reinterpret_cast<const float4*>(ssf + 256)[lane];
    float4 sx = reinterpret_cast<const float4*>(sss)[lane];
    float4 cx = reinterpret_cast<const float4*>(sss + 256)[lane];

    ushort4 o;
    {
        float v = w0 * toF((u16)a0.x) + w1 * toF((u16)a1.x) + w2 * toF((u16)a2.x);
        float val = v * sf.x + cf.x + toF((u16)sk.x) * sx.x + cx.x;
        o.x = f2bf(fmaxf(val, 0.f));
    }
    {
        float v = w0 * toF((u16)a0.y) + w1 * toF((u16)a1.y) + w2 * toF((u16)a2.y);
        float val = v * sf.y + cf.y + toF((u16)sk.y) * sx.y + cx.y;
        o.y = f2bf(fmaxf(val, 0.f));
    }
    {
        float v = w0 * toF((u16)a0.z) + w1 * toF((u16)a1.z) + w2 * toF((u16)a2.z);
        float val = v * sf.z + cf.z + toF((u16)sk.z) * sx.z + cx.z;
        o.z = f2bf(fmaxf(val, 0.f));
    }
    {
        float v = w0 * toF((u16)a0.w) + w1 * toF((u16)a1.w) + w2 * toF((u16)a2.w);
        float val = v * sf.w + cf.w + toF((u16)sk.w) * sx.w + cx.w;
        o.w = f2bf(fmaxf(val, 0.f));
    }
    reinterpret_cast<ushort4*>(x + (size_t)row * 256)[lane] = o;
}

// ---------------------------------------------------------------------------
// out = relu(out * scale + shift), in place, float4-vectorized
// ---------------------------------------------------------------------------
__global__ __launch_bounds__(256) void bn_relu_inplace(
    float* __restrict__ out, const float* __restrict__ ss)
{
    size_t i4 = (size_t)blockIdx.x * 256 + threadIdx.x;
    int c4 = (int)(i4 & 63);
    float4 v = reinterpret_cast<float4*>(out)[i4];
    float4 sc = reinterpret_cast<const float4*>(ss)[c4];
    float4 sh = reinterpret_cast<const float4*>(ss + 256)[c4];
    v.x = fmaxf(fmaf(v.x, sc.x, sh.x), 0.f);
    v.y = fmaxf(fmaf(v.y, sc.y, sh.y), 0.f);
    v.z = fmaxf(fmaf(v.z, sc.z, sh.z), 0.f);
    v.w = fmaxf(fmaf(v.w, sc.w, sh.w), 0.f);
    reinterpret_cast<float4*>(out)[i4] = v;
}

// ---------------------------------------------------------------------------
extern "C" void kernel_launch(void* const* d_in, const int* in_sizes, int n_in,
                              void* d_out, int out_size, void* d_ws, size_t ws_size,
                              hipStream_t stream) {
    const float* points1 = (const float*)d_in[0];
    const float* points2 = (const float*)d_in[1];
    const float* dist    = (const float*)d_in[2];
    const int*   idx     = (const int*)d_in[3];
    const float* Wf0     = (const float*)d_in[4];
    const float* bf0     = (const float*)d_in[5];
    const float* gf0     = (const float*)d_in[6];
    const float* betaf0  = (const float*)d_in[7];
    const float* Ws0     = (const float*)d_in[8];
    const float* bs0     = (const float*)d_in[9];
    const float* gs0     = (const float*)d_in[10];
    const float* betas0  = (const float*)d_in[11];
    const float* W1      = (const float*)d_in[12];
    const float* b1      = (const float*)d_in[13];
    const float* g1      = (const float*)d_in[14];
    const float* beta1   = (const float*)d_in[15];

    char* ws = (char*)d_ws;
    u16* y2   = (u16*)ws;                                             // N2*256 bf16 = 32MB
    u16* xbuf = (u16*)(ws + (size_t)CN2 * 256 * 2);                   // N1*256 bf16 = 128MB
    float* partial = (float*)(ws + (size_t)CN2 * 256 * 2 + (size_t)CN1 * 256 * 2); // 2MB
    float* ss_f0 = partial + 1024 * 512;
    float* ss_s0 = ss_f0 + 512;
    float* ss_1  = ss_s0 + 512;
    float* out = (float*)d_out;

    // 1) y2 = points2 @ Wf0 + bf0   [N2 x 256], bf16
    gemm_bias_256<float, u16><<<dim3(CN2 / 128, 2), 256, 0, stream>>>(
        points2, Wf0, bf0, y2, CN2, CPREV);
    // 2) f0 batch-norm stats -> scale/shift
    colstats_partial<u16><<<256, 256, 0, stream>>>(y2, CN2 / 256, partial);
    colstats_final<<<1, 256, 0, stream>>>(partial, 256, 1.0f / CN2, gf0, betaf0, ss_f0);
    // 3) skip_pre = points1 @ Ws0 + bs0   [N1 x 256], bf16 (stored in xbuf)
    gemm_bias_256<float, u16><<<dim3(CN1 / 128, 2), 256, 0, stream>>>(
        points1, Ws0, bs0, xbuf, CN1, CSKIP);
    // 4) s0 stats
    colstats_partial<u16><<<1024, 256, 0, stream>>>(xbuf, CN1 / 1024, partial);
    colstats_final<<<1, 256, 0, stream>>>(partial, 1024, 1.0f / CN1, gs0, betas0, ss_s0);
    // 5) x = relu(interp + skip) in place in xbuf
    interp_relu<<<CN1 / 4, 256, 0, stream>>>(y2, xbuf, dist, idx, ss_f0, ss_s0);
    // 6) y3 = x @ W1 + b1 -> d_out (pre-BN, f32)
    gemm_bias_256<u16, float><<<dim3(CN1 / 128, 2), 256, 0, stream>>>(
        xbuf, W1, b1, out, CN1, 256);
    // 7) layer-1 stats
    colstats_partial<float><<<1024, 256, 0, stream>>>(out, CN1 / 1024, partial);
    colstats_final<<<1, 256, 0, stream>>>(partial, 1024, 1.0f / CN1, g1, beta1, ss_1);
    // 8) out = relu(bn(out)) in place
    bn_relu_inplace<<<CN1 / 4, 256, 0, stream>>>(out, ss_1);
}

// Round 2
// 1322.926 us; speedup vs baseline: 1.5791x; 1.5791x over previous
//
#include <hip/hip_runtime.h>
#include <hip/hip_bf16.h>

// Problem constants
#define CN1 262144
#define CN2 65536
#define CPREV 512
#define CSKIP 256

using u16 = unsigned short;

typedef __attribute__((ext_vector_type(8))) short short8;
typedef __attribute__((ext_vector_type(8))) unsigned short ushort8;
typedef __attribute__((ext_vector_type(4))) float f32x4;

__device__ __forceinline__ float toF(float v) { return v; }
__device__ __forceinline__ float toF(u16 u) { return __uint_as_float(((unsigned)u) << 16); }
__device__ __forceinline__ u16 f2bf(float f) {
    unsigned b = __float_as_uint(f);
    b += 0x7FFFu + ((b >> 16) & 1u);
    return (u16)(b >> 16);
}
__device__ __forceinline__ unsigned pack2(float lo, float hi) {
    return ((unsigned)f2bf(hi) << 16) | (unsigned)f2bf(lo);
}

// ---------------------------------------------------------------------------
// Weight transpose+convert: Wt[n][k] (bf16) = W[k][n] (f32). 256*K elements.
// ---------------------------------------------------------------------------
__global__ __launch_bounds__(256) void transpose_w(
    const float* __restrict__ W, u16* __restrict__ Wt, int ksh)
{
    int e = blockIdx.x * 256 + threadIdx.x;      // e < 256*K
    int K = 1 << ksh;
    int n = e >> ksh;
    int k = e & (K - 1);
    Wt[e] = f2bf(W[((size_t)k << 8) + n]);
}

// ---------------------------------------------------------------------------
// MFMA GEMM: C[M x 256] = A[M x K] @ W[K x 256] + bias.
// A f32 (converted during staging) or bf16. W given as Wt[n][k] bf16.
// BM=128, BN=256 (full), BK=32. 512 threads = 8 waves (2x4), 64x64 per wave.
// LDS pitch 40 u16 (80B) -> fragment ds_read_b128 is 2-way conflict = free.
// ---------------------------------------------------------------------------
template<bool AF32, typename OT>
__global__ __launch_bounds__(512) void gemm_mfma(
    const void* __restrict__ Av, const u16* __restrict__ Wt,
    const float* __restrict__ bias, OT* __restrict__ C,
    int M, int K)
{
    __shared__ u16 As[128 * 40];
    __shared__ u16 Bs[256 * 40];
    const int t = threadIdx.x;
    const int bm = blockIdx.x * 128;
    const int lane = t & 63;
    const int wid = t >> 6;
    const int wr = wid >> 2;       // 0..1
    const int wc = wid & 3;        // 0..3

    const int arow = t >> 2;       // 0..127
    const int koff = (t & 3) * 8;  // 0,8,16,24

    const float* Af = (const float*)Av;
    const u16*   Ab = (const u16*)Av;

    f32x4 acc[4][4] = {};

    float4 ga0, ga1;
    ushort8 gab, gb0, gb1;

    auto LOAD = [&](int k0) {
        if constexpr (AF32) {
            const float* p = Af + (size_t)(bm + arow) * K + k0 + koff;
            ga0 = *(const float4*)p;
            ga1 = *(const float4*)(p + 4);
        } else {
            gab = *(const ushort8*)(Ab + (size_t)(bm + arow) * K + k0 + koff);
        }
        const u16* q = Wt + (size_t)arow * K + k0 + koff;
        gb0 = *(const ushort8*)q;
        gb1 = *(const ushort8*)(q + (size_t)128 * K);
    };

    const int nk = K >> 5;
    LOAD(0);
    for (int it = 0; it < nk; ++it) {
        __syncthreads();   // previous iter's fragment reads complete
        if constexpr (AF32) {
            uint4 w;
            w.x = pack2(ga0.x, ga0.y);
            w.y = pack2(ga0.z, ga0.w);
            w.z = pack2(ga1.x, ga1.y);
            w.w = pack2(ga1.z, ga1.w);
            *(uint4*)&As[arow * 40 + koff] = w;
        } else {
            *(ushort8*)&As[arow * 40 + koff] = gab;
        }
        *(ushort8*)&Bs[arow * 40 + koff] = gb0;
        *(ushort8*)&Bs[(128 + arow) * 40 + koff] = gb1;
        __syncthreads();
        if (it + 1 < nk) LOAD((it + 1) << 5);   // next loads fly under MFMA

        const int kq = (lane >> 4) * 8;
        const int rr = lane & 15;
        short8 af[4];
#pragma unroll
        for (int mi = 0; mi < 4; ++mi)
            af[mi] = *(const short8*)&As[(wr * 64 + mi * 16 + rr) * 40 + kq];
#pragma unroll
        for (int ni = 0; ni < 4; ++ni) {
            short8 bf = *(const short8*)&Bs[(wc * 64 + ni * 16 + rr) * 40 + kq];
#pragma unroll
            for (int mi = 0; mi < 4; ++mi)
                acc[mi][ni] = __builtin_amdgcn_mfma_f32_16x16x32_bf16(
                    af[mi], bf, acc[mi][ni], 0, 0, 0);
        }
    }

    // epilogue: C/D layout col=lane&15, row=(lane>>4)*4+j
    const int r4 = (lane >> 4) * 4;
    const int cc = lane & 15;
#pragma unroll
    for (int ni = 0; ni < 4; ++ni) {
        int col = wc * 64 + ni * 16 + cc;
        float bv = bias[col];
#pragma unroll
        for (int mi = 0; mi < 4; ++mi) {
            size_t r0 = (size_t)bm + wr * 64 + mi * 16 + r4;
            f32x4 v = acc[mi][ni];
#pragma unroll
            for (int j = 0; j < 4; ++j) {
                float val = v[j] + bv;
                if constexpr (sizeof(OT) == 4)
                    C[(r0 + j) * 256 + col] = val;
                else
                    C[(r0 + j) * 256 + col] = f2bf(val);
            }
        }
    }
}

// ---------------------------------------------------------------------------
// Column stats: per-block partial sum / sumsq over a stripe of rows (width 256)
// ---------------------------------------------------------------------------
template<typename T>
__global__ __launch_bounds__(256) void colstats_partial(
    const T* __restrict__ X, int rpb, float* __restrict__ partial)
{
    int c = threadIdx.x;
    size_t r0 = (size_t)blockIdx.x * rpb;
    float s = 0.f, s2 = 0.f;
    for (int r = 0; r < rpb; ++r) {
        float v = toF(X[(r0 + r) * 256 + c]);
        s += v;
        s2 = fmaf(v, v, s2);
    }
    partial[(size_t)blockIdx.x * 512 + c] = s;
    partial[(size_t)blockIdx.x * 512 + 256 + c] = s2;
}

__global__ __launch_bounds__(256) void colstats_final(
    const float* __restrict__ partial, int nb, float invR,
    const float* __restrict__ g, const float* __restrict__ beta,
    float* __restrict__ ss)
{
    int c = threadIdx.x;
    float s = 0.f, s2 = 0.f;
    for (int b = 0; b < nb; ++b) {
        s += partial[(size_t)b * 512 + c];
        s2 += partial[(size_t)b * 512 + 256 + c];
    }
    float m = s * invR;
    float var = fmaf(-m, m, s2 * invR);
    float scale = g[c] * rsqrtf(var + 1e-5f);
    ss[c] = scale;
    ss[256 + c] = fmaf(-m, scale, beta[c]);
}

// ---------------------------------------------------------------------------
// x = relu( (sum_k w_k * y2[idx_k]) * sf + cf  +  skip * ssx + csx ), in place
// ---------------------------------------------------------------------------
__global__ __launch_bounds__(256) void interp_relu(
    const u16* __restrict__ y2, u16* __restrict__ x,
    const float* __restrict__ dist, const int* __restrict__ idx,
    const float* __restrict__ ssf, const float* __restrict__ sss)
{
    int row = blockIdx.x * 4 + (threadIdx.x >> 6);
    int lane = threadIdx.x & 63;

    float d0 = dist[row * 3 + 0], d1 = dist[row * 3 + 1], d2 = dist[row * 3 + 2];
    float r0 = 1.f / (d0 + 1e-8f), r1 = 1.f / (d1 + 1e-8f), r2 = 1.f / (d2 + 1e-8f);
    float inv = 1.f / (r0 + r1 + r2);
    float w0 = r0 * inv, w1 = r1 * inv, w2 = r2 * inv;
    int i0 = idx[row * 3 + 0], i1 = idx[row * 3 + 1], i2 = idx[row * 3 + 2];

    ushort4 a0 = reinterpret_cast<const ushort4*>(y2 + (size_t)i0 * 256)[lane];
    ushort4 a1 = reinterpret_cast<const ushort4*>(y2 + (size_t)i1 * 256)[lane];
    ushort4 a2 = reinterpret_cast<const ushort4*>(y2 + (size_t)i2 * 256)[lane];
    ushort4 sk = reinterpret_cast<const ushort4*>(x + (size_t)row * 256)[lane];

    float4 sf = reinterpret_cast<const float4*>(ssf)[lane];
    float4 cf = reinterpret_cast<const float4*>(ssf + 256)[lane];
    float4 sx = reinterpret_cast<const float4*>(sss)[lane];
    float4 cx = reinterpret_cast<const float4*>(sss + 256)[lane];

    ushort4 o;
    {
        float v = w0 * toF((u16)a0.x) + w1 * toF((u16)a1.x) + w2 * toF((u16)a2.x);
        float val = v * sf.x + cf.x + toF((u16)sk.x) * sx.x + cx.x;
        o.x = f2bf(fmaxf(val, 0.f));
    }
    {
        float v = w0 * toF((u16)a0.y) + w1 * toF((u16)a1.y) + w2 * toF((u16)a2.y);
        float val = v * sf.y + cf.y + toF((u16)sk.y) * sx.y + cx.y;
        o.y = f2bf(fmaxf(val, 0.f));
    }
    {
        float v = w0 * toF((u16)a0.z) + w1 * toF((u16)a1.z) + w2 * toF((u16)a2.z);
        float val = v * sf.z + cf.z + toF((u16)sk.z) * sx.z + cx.z;
        o.z = f2bf(fmaxf(val, 0.f));
    }
    {
        float v = w0 * toF((u16)a0.w) + w1 * toF((u16)a1.w) + w2 * toF((u16)a2.w);
        float val = v * sf.w + cf.w + toF((u16)sk.w) * sx.w + cx.w;
        o.w = f2bf(fmaxf(val, 0.f));
    }
    reinterpret_cast<ushort4*>(x + (size_t)row * 256)[lane] = o;
}

// ---------------------------------------------------------------------------
// out = relu(out * scale + shift), in place, float4-vectorized
// ---------------------------------------------------------------------------
__global__ __launch_bounds__(256) void bn_relu_inplace(
    float* __restrict__ out, const float* __restrict__ ss)
{
    size_t i4 = (size_t)blockIdx.x * 256 + threadIdx.x;
    int c4 = (int)(i4 & 63);
    float4 v = reinterpret_cast<float4*>(out)[i4];
    float4 sc = reinterpret_cast<const float4*>(ss)[c4];
    float4 sh = reinterpret_cast<const float4*>(ss + 256)[c4];
    v.x = fmaxf(fmaf(v.x, sc.x, sh.x), 0.f);
    v.y = fmaxf(fmaf(v.y, sc.y, sh.y), 0.f);
    v.z = fmaxf(fmaf(v.z, sc.z, sh.z), 0.f);
    v.w = fmaxf(fmaf(v.w, sc.w, sh.w), 0.f);
    reinterpret_cast<float4*>(out)[i4] = v;
}

// ---------------------------------------------------------------------------
extern "C" void kernel_launch(void* const* d_in, const int* in_sizes, int n_in,
                              void* d_out, int out_size, void* d_ws, size_t ws_size,
                              hipStream_t stream) {
    const float* points1 = (const float*)d_in[0];
    const float* points2 = (const float*)d_in[1];
    const float* dist    = (const float*)d_in[2];
    const int*   idx     = (const int*)d_in[3];
    const float* Wf0     = (const float*)d_in[4];
    const float* bf0     = (const float*)d_in[5];
    const float* gf0     = (const float*)d_in[6];
    const float* betaf0  = (const float*)d_in[7];
    const float* Ws0     = (const float*)d_in[8];
    const float* bs0     = (const float*)d_in[9];
    const float* gs0     = (const float*)d_in[10];
    const float* betas0  = (const float*)d_in[11];
    const float* W1      = (const float*)d_in[12];
    const float* b1      = (const float*)d_in[13];
    const float* g1      = (const float*)d_in[14];
    const float* beta1   = (const float*)d_in[15];

    u16* ws = (u16*)d_ws;
    u16* y2   = ws;                                   // N2*256 bf16 = 32MB
    u16* xbuf = y2 + (size_t)CN2 * 256;               // N1*256 bf16 = 128MB
    u16* Wtf0 = xbuf + (size_t)CN1 * 256;             // 512*256 bf16
    u16* Wts0 = Wtf0 + 512 * 256;                     // 256*256 bf16
    u16* Wt1  = Wts0 + 256 * 256;                     // 256*256 bf16
    float* partial = (float*)(Wt1 + 256 * 256);       // 1024*512 f32 = 2MB
    float* ss_f0 = partial + 1024 * 512;
    float* ss_s0 = ss_f0 + 512;
    float* ss_1  = ss_s0 + 512;
    float* out = (float*)d_out;

    // weight transposes (f32 -> bf16, [K][256] -> [256][K])
    transpose_w<<<512, 256, 0, stream>>>(Wf0, Wtf0, 9);
    transpose_w<<<256, 256, 0, stream>>>(Ws0, Wts0, 8);
    transpose_w<<<256, 256, 0, stream>>>(W1, Wt1, 8);

    // 1) y2 = points2 @ Wf0 + bf0   [N2 x 256], bf16
    gemm_mfma<true, u16><<<CN2 / 128, 512, 0, stream>>>(
        points2, Wtf0, bf0, y2, CN2, CPREV);
    // 2) f0 stats -> scale/shift
    colstats_partial<u16><<<256, 256, 0, stream>>>(y2, CN2 / 256, partial);
    colstats_final<<<1, 256, 0, stream>>>(partial, 256, 1.0f / CN2, gf0, betaf0, ss_f0);
    // 3) skip_pre = points1 @ Ws0 + bs0   [N1 x 256], bf16
    gemm_mfma<true, u16><<<CN1 / 128, 512, 0, stream>>>(
        points1, Wts0, bs0, xbuf, CN1, CSKIP);
    // 4) s0 stats
    colstats_partial<u16><<<1024, 256, 0, stream>>>(xbuf, CN1 / 1024, partial);
    colstats_final<<<1, 256, 0, stream>>>(partial, 1024, 1.0f / CN1, gs0, betas0, ss_s0);
    // 5) x = relu(interp + skip) in place
    interp_relu<<<CN1 / 4, 256, 0, stream>>>(y2, xbuf, dist, idx, ss_f0, ss_s0);
    // 6) y3 = x @ W1 + b1 -> d_out (pre-BN, f32)
    gemm_mfma<false, float><<<CN1 / 128, 512, 0, stream>>>(
        xbuf, Wt1, b1, out, CN1, 256);
    // 7) layer-1 stats
    colstats_partial<float><<<1024, 256, 0, stream>>>(out, CN1 / 1024, partial);
    colstats_final<<<1, 256, 0, stream>>>(partial, 1024, 1.0f / CN1, g1, beta1, ss_1);
    // 8) out = relu(bn(out)) in place
    bn_relu_inplace<<<CN1 / 4, 256, 0, stream>>>(out, ss_1);
}

// Round 5
// 534.584 us; speedup vs baseline: 3.9079x; 2.4747x over previous
//
#include <hip/hip_runtime.h>
#include <hip/hip_bf16.h>

// Problem constants
#define CN1 262144
#define CN2 65536
#define CPREV 512
#define CSKIP 256

using u16 = unsigned short;

typedef __attribute__((ext_vector_type(8))) short short8;
typedef __attribute__((ext_vector_type(8))) unsigned short ushort8;
typedef __attribute__((ext_vector_type(4))) float f32x4;

__device__ __forceinline__ float toF(float v) { return v; }
__device__ __forceinline__ float toF(u16 u) { return __uint_as_float(((unsigned)u) << 16); }
__device__ __forceinline__ u16 f2bf(float f) {
    unsigned b = __float_as_uint(f);
    b += 0x7FFFu + ((b >> 16) & 1u);
    return (u16)(b >> 16);
}
__device__ __forceinline__ unsigned pack2(float lo, float hi) {
    return ((unsigned)f2bf(hi) << 16) | (unsigned)f2bf(lo);
}

// ---------------------------------------------------------------------------
// Weight transpose+convert: Wt[n][k] (bf16) = W[k][n] (f32). 256*K elements.
// ---------------------------------------------------------------------------
__global__ __launch_bounds__(256) void transpose_w(
    const float* __restrict__ W, u16* __restrict__ Wt, int ksh)
{
    int e = blockIdx.x * 256 + threadIdx.x;      // e < 256*K
    int K = 1 << ksh;
    int n = e >> ksh;
    int k = e & (K - 1);
    Wt[e] = f2bf(W[((size_t)k << 8) + n]);
}

// ---------------------------------------------------------------------------
// MFMA GEMM: C[M x 256] = A[M x K] @ W[K x 256] + bias.
// A f32 (converted during staging) or bf16. W given as Wt[n][k] bf16.
// BM=128, BN=256 (full), BK=32. 512 threads = 8 waves (2x4), 64x64 per wave.
// Epilogue additionally emits per-block column sum/sumsq partials (for BN).
// ---------------------------------------------------------------------------
template<bool AF32, typename OT>
__global__ __launch_bounds__(512) void gemm_mfma(
    const void* __restrict__ Av, const u16* __restrict__ Wt,
    const float* __restrict__ bias, OT* __restrict__ C,
    float* __restrict__ partial, int M, int K)
{
    __shared__ u16 As[128 * 40];
    __shared__ u16 Bs[256 * 40];
    const int t = threadIdx.x;
    const int bm = blockIdx.x * 128;
    const int lane = t & 63;
    const int wid = t >> 6;
    const int wr = wid >> 2;       // 0..1
    const int wc = wid & 3;        // 0..3

    const int arow = t >> 2;       // 0..127
    const int koff = (t & 3) * 8;  // 0,8,16,24

    const float* Af = (const float*)Av;
    const u16*   Ab = (const u16*)Av;

    f32x4 acc[4][4] = {};

    float4 ga0, ga1;
    ushort8 gab, gb0, gb1;

    auto LOAD = [&](int k0) {
        if constexpr (AF32) {
            const float* p = Af + (size_t)(bm + arow) * K + k0 + koff;
            ga0 = *(const float4*)p;
            ga1 = *(const float4*)(p + 4);
        } else {
            gab = *(const ushort8*)(Ab + (size_t)(bm + arow) * K + k0 + koff);
        }
        const u16* q = Wt + (size_t)arow * K + k0 + koff;
        gb0 = *(const ushort8*)q;
        gb1 = *(const ushort8*)(q + (size_t)128 * K);
    };

    const int nk = K >> 5;
    LOAD(0);
    for (int it = 0; it < nk; ++it) {
        __syncthreads();   // previous iter's fragment reads complete
        if constexpr (AF32) {
            uint4 w;
            w.x = pack2(ga0.x, ga0.y);
            w.y = pack2(ga0.z, ga0.w);
            w.z = pack2(ga1.x, ga1.y);
            w.w = pack2(ga1.z, ga1.w);
            *(uint4*)&As[arow * 40 + koff] = w;
        } else {
            *(ushort8*)&As[arow * 40 + koff] = gab;
        }
        *(ushort8*)&Bs[arow * 40 + koff] = gb0;
        *(ushort8*)&Bs[(128 + arow) * 40 + koff] = gb1;
        __syncthreads();
        if (it + 1 < nk) LOAD((it + 1) << 5);   // next loads fly under MFMA

        const int kq = (lane >> 4) * 8;
        const int rr = lane & 15;
        short8 af[4];
#pragma unroll
        for (int mi = 0; mi < 4; ++mi)
            af[mi] = *(const short8*)&As[(wr * 64 + mi * 16 + rr) * 40 + kq];
#pragma unroll
        for (int ni = 0; ni < 4; ++ni) {
            short8 bf = *(const short8*)&Bs[(wc * 64 + ni * 16 + rr) * 40 + kq];
#pragma unroll
            for (int mi = 0; mi < 4; ++mi)
                acc[mi][ni] = __builtin_amdgcn_mfma_f32_16x16x32_bf16(
                    af[mi], bf, acc[mi][ni], 0, 0, 0);
        }
    }

    __syncthreads();   // fragment reads done everywhere; LDS reusable
    // epilogue: C/D layout col=lane&15, row=(lane>>4)*4+j; also col stats
    float* cs  = (float*)As;         // [2][256] column sums (per wave-row)
    float* cs2 = ((float*)As) + 512; // [2][256] column sumsq
    const int r4 = (lane >> 4) * 4;
    const int cc = lane & 15;
#pragma unroll
    for (int ni = 0; ni < 4; ++ni) {
        int col = wc * 64 + ni * 16 + cc;
        float bv = bias[col];
        float s = 0.f, s2 = 0.f;
#pragma unroll
        for (int mi = 0; mi < 4; ++mi) {
            size_t r0 = (size_t)bm + wr * 64 + mi * 16 + r4;
            f32x4 v = acc[mi][ni];
#pragma unroll
            for (int j = 0; j < 4; ++j) {
                float val = v[j] + bv;
                s += val;
                s2 = fmaf(val, val, s2);
                if constexpr (sizeof(OT) == 4)
                    C[(r0 + j) * 256 + col] = val;
                else
                    C[(r0 + j) * 256 + col] = f2bf(val);
            }
        }
        s  += __shfl_xor(s, 16);  s  += __shfl_xor(s, 32);
        s2 += __shfl_xor(s2, 16); s2 += __shfl_xor(s2, 32);
        if (lane < 16) { cs[wr * 256 + col] = s; cs2[wr * 256 + col] = s2; }
    }
    __syncthreads();
    if (t < 256) {
        partial[(size_t)blockIdx.x * 512 + t]       = cs[t] + cs[256 + t];
        partial[(size_t)blockIdx.x * 512 + 256 + t] = cs2[t] + cs2[256 + t];
    }
}

// ---------------------------------------------------------------------------
// Stats finalize: one block per column. Reduce nb block-partials, emit
// scale/shift for BN.
// ---------------------------------------------------------------------------
__global__ __launch_bounds__(256) void colstats_final_par(
    const float* __restrict__ partial, int nb, float invR,
    const float* __restrict__ g, const float* __restrict__ beta,
    float* __restrict__ ss)
{
    int c = blockIdx.x;
    int t = threadIdx.x;
    float s = 0.f, s2 = 0.f;
    for (int b = t; b < nb; b += 256) {
        s  += partial[(size_t)b * 512 + c];
        s2 += partial[(size_t)b * 512 + 256 + c];
    }
#pragma unroll
    for (int o = 32; o > 0; o >>= 1) {
        s += __shfl_xor(s, o);
        s2 += __shfl_xor(s2, o);
    }
    __shared__ float rs[4], rs2[4];
    if ((t & 63) == 0) { rs[t >> 6] = s; rs2[t >> 6] = s2; }
    __syncthreads();
    if (t == 0) {
        float S  = rs[0] + rs[1] + rs[2] + rs[3];
        float S2 = rs2[0] + rs2[1] + rs2[2] + rs2[3];
        float m = S * invR;
        float var = fmaf(-m, m, S2 * invR);
        float scale = g[c] * rsqrtf(var + 1e-5f);
        ss[c] = scale;
        ss[256 + c] = fmaf(-m, scale, beta[c]);
    }
}

// ---------------------------------------------------------------------------
// x = relu( (sum_k w_k * y2[idx_k]) * sf + cf  +  skip * ssx + csx ), in place
// ---------------------------------------------------------------------------
__global__ __launch_bounds__(256) void interp_relu(
    const u16* __restrict__ y2, u16* __restrict__ x,
    const float* __restrict__ dist, const int* __restrict__ idx,
    const float* __restrict__ ssf, const float* __restrict__ sss)
{
    int row = blockIdx.x * 4 + (threadIdx.x >> 6);
    int lane = threadIdx.x & 63;

    float d0 = dist[row * 3 + 0], d1 = dist[row * 3 + 1], d2 = dist[row * 3 + 2];
    float r0 = 1.f / (d0 + 1e-8f), r1 = 1.f / (d1 + 1e-8f), r2 = 1.f / (d2 + 1e-8f);
    float inv = 1.f / (r0 + r1 + r2);
    float w0 = r0 * inv, w1 = r1 * inv, w2 = r2 * inv;
    int i0 = idx[row * 3 + 0], i1 = idx[row * 3 + 1], i2 = idx[row * 3 + 2];

    ushort4 a0 = reinterpret_cast<const ushort4*>(y2 + (size_t)i0 * 256)[lane];
    ushort4 a1 = reinterpret_cast<const ushort4*>(y2 + (size_t)i1 * 256)[lane];
    ushort4 a2 = reinterpret_cast<const ushort4*>(y2 + (size_t)i2 * 256)[lane];
    ushort4 sk = reinterpret_cast<const ushort4*>(x + (size_t)row * 256)[lane];

    float4 sf = reinterpret_cast<const float4*>(ssf)[lane];
    float4 cf = reinterpret_cast<const float4*>(ssf + 256)[lane];
    float4 sx = reinterpret_cast<const float4*>(sss)[lane];
    float4 cx = reinterpret_cast<const float4*>(sss + 256)[lane];

    ushort4 o;
    {
        float v = w0 * toF((u16)a0.x) + w1 * toF((u16)a1.x) + w2 * toF((u16)a2.x);
        float val = v * sf.x + cf.x + toF((u16)sk.x) * sx.x + cx.x;
        o.x = f2bf(fmaxf(val, 0.f));
    }
    {
        float v = w0 * toF((u16)a0.y) + w1 * toF((u16)a1.y) + w2 * toF((u16)a2.y);
        float val = v * sf.y + cf.y + toF((u16)sk.y) * sx.y + cx.y;
        o.y = f2bf(fmaxf(val, 0.f));
    }
    {
        float v = w0 * toF((u16)a0.z) + w1 * toF((u16)a1.z) + w2 * toF((u16)a2.z);
        float val = v * sf.z + cf.z + toF((u16)sk.z) * sx.z + cx.z;
        o.z = f2bf(fmaxf(val, 0.f));
    }
    {
        float v = w0 * toF((u16)a0.w) + w1 * toF((u16)a1.w) + w2 * toF((u16)a2.w);
        float val = v * sf.w + cf.w + toF((u16)sk.w) * sx.w + cx.w;
        o.w = f2bf(fmaxf(val, 0.f));
    }
    reinterpret_cast<ushort4*>(x + (size_t)row * 256)[lane] = o;
}

// ---------------------------------------------------------------------------
// out = relu(out * scale + shift), in place, float4-vectorized
// ---------------------------------------------------------------------------
__global__ __launch_bounds__(256) void bn_relu_inplace(
    float* __restrict__ out, const float* __restrict__ ss)
{
    size_t i4 = (size_t)blockIdx.x * 256 + threadIdx.x;
    int c4 = (int)(i4 & 63);
    float4 v = reinterpret_cast<float4*>(out)[i4];
    float4 sc = reinterpret_cast<const float4*>(ss)[c4];
    float4 sh = reinterpret_cast<const float4*>(ss + 256)[c4];
    v.x = fmaxf(fmaf(v.x, sc.x, sh.x), 0.f);
    v.y = fmaxf(fmaf(v.y, sc.y, sh.y), 0.f);
    v.z = fmaxf(fmaf(v.z, sc.z, sh.z), 0.f);
    v.w = fmaxf(fmaf(v.w, sc.w, sh.w), 0.f);
    reinterpret_cast<float4*>(out)[i4] = v;
}

// ---------------------------------------------------------------------------
extern "C" void kernel_launch(void* const* d_in, const int* in_sizes, int n_in,
                              void* d_out, int out_size, void* d_ws, size_t ws_size,
                              hipStream_t stream) {
    const float* points1 = (const float*)d_in[0];
    const float* points2 = (const float*)d_in[1];
    const float* dist    = (const float*)d_in[2];
    const int*   idx     = (const int*)d_in[3];
    const float* Wf0     = (const float*)d_in[4];
    const float* bf0     = (const float*)d_in[5];
    const float* gf0     = (const float*)d_in[6];
    const float* betaf0  = (const float*)d_in[7];
    const float* Ws0     = (const float*)d_in[8];
    const float* bs0     = (const float*)d_in[9];
    const float* gs0     = (const float*)d_in[10];
    const float* betas0  = (const float*)d_in[11];
    const float* W1      = (const float*)d_in[12];
    const float* b1      = (const float*)d_in[13];
    const float* g1      = (const float*)d_in[14];
    const float* beta1   = (const float*)d_in[15];

    u16* ws = (u16*)d_ws;
    u16* y2   = ws;                                   // N2*256 bf16 = 32MB
    u16* xbuf = y2 + (size_t)CN2 * 256;               // N1*256 bf16 = 128MB
    u16* Wtf0 = xbuf + (size_t)CN1 * 256;             // 512*256 bf16
    u16* Wts0 = Wtf0 + 512 * 256;                     // 256*256 bf16
    u16* Wt1  = Wts0 + 256 * 256;                     // 256*256 bf16
    float* partial = (float*)(Wt1 + 256 * 256);       // 2048*512 f32 = 4MB
    float* ss_f0 = partial + 2048 * 512;
    float* ss_s0 = ss_f0 + 512;
    float* ss_1  = ss_s0 + 512;
    float* out = (float*)d_out;

    // weight transposes (f32 -> bf16, [K][256] -> [256][K])
    transpose_w<<<512, 256, 0, stream>>>(Wf0, Wtf0, 9);
    transpose_w<<<256, 256, 0, stream>>>(Ws0, Wts0, 8);
    transpose_w<<<256, 256, 0, stream>>>(W1, Wt1, 8);

    // 1) y2 = points2 @ Wf0 + bf0   [N2 x 256], bf16 (+ col partials)
    gemm_mfma<true, u16><<<CN2 / 128, 512, 0, stream>>>(
        points2, Wtf0, bf0, y2, partial, CN2, CPREV);
    colstats_final_par<<<256, 256, 0, stream>>>(partial, CN2 / 128, 1.0f / CN2,
                                                gf0, betaf0, ss_f0);
    // 2) skip_pre = points1 @ Ws0 + bs0   [N1 x 256], bf16 (+ col partials)
    gemm_mfma<true, u16><<<CN1 / 128, 512, 0, stream>>>(
        points1, Wts0, bs0, xbuf, partial, CN1, CSKIP);
    colstats_final_par<<<256, 256, 0, stream>>>(partial, CN1 / 128, 1.0f / CN1,
                                                gs0, betas0, ss_s0);
    // 3) x = relu(interp + skip) in place
    interp_relu<<<CN1 / 4, 256, 0, stream>>>(y2, xbuf, dist, idx, ss_f0, ss_s0);
    // 4) y3 = x @ W1 + b1 -> d_out (pre-BN, f32) (+ col partials)
    gemm_mfma<false, float><<<CN1 / 128, 512, 0, stream>>>(
        xbuf, Wt1, b1, out, partial, CN1, 256);
    colstats_final_par<<<256, 256, 0, stream>>>(partial, CN1 / 128, 1.0f / CN1,
                                                g1, beta1, ss_1);
    // 5) out = relu(bn(out)) in place
    bn_relu_inplace<<<CN1 / 4, 256, 0, stream>>>(out, ss_1);
}

// Round 6
// 490.903 us; speedup vs baseline: 4.2556x; 1.0890x over previous
//
#include <hip/hip_runtime.h>
#include <hip/hip_bf16.h>

// Problem constants
#define CN1 262144
#define CN2 65536
#define CPREV 512
#define CSKIP 256

using u16 = unsigned short;

typedef __attribute__((ext_vector_type(8))) short short8;
typedef __attribute__((ext_vector_type(8))) unsigned short ushort8;
typedef __attribute__((ext_vector_type(4))) float f32x4;
typedef __attribute__((ext_vector_type(8))) float f32x8;

__device__ __forceinline__ float toF(float v) { return v; }
__device__ __forceinline__ float toF(u16 u) { return __uint_as_float(((unsigned)u) << 16); }
__device__ __forceinline__ u16 f2bf(float f) {
    unsigned b = __float_as_uint(f);
    b += 0x7FFFu + ((b >> 16) & 1u);
    return (u16)(b >> 16);
}
__device__ __forceinline__ unsigned pack2(float lo, float hi) {
    return ((unsigned)f2bf(hi) << 16) | (unsigned)f2bf(lo);
}

// ---------------------------------------------------------------------------
// All three weight transposes in one launch: Wt[n][k] (bf16) = W[k][n] (f32).
// blocks 0..511 -> Wf0 (K=512), 512..767 -> Ws0 (K=256), 768..1023 -> W1.
// ---------------------------------------------------------------------------
__global__ __launch_bounds__(256) void transpose_all(
    const float* __restrict__ Wf0, const float* __restrict__ Ws0,
    const float* __restrict__ W1,
    u16* __restrict__ Wtf0, u16* __restrict__ Wts0, u16* __restrict__ Wt1)
{
    int b = blockIdx.x;
    const float* W; u16* Wt; int ksh, e;
    if (b < 512)      { W = Wf0; Wt = Wtf0; ksh = 9; e = b * 256 + threadIdx.x; }
    else if (b < 768) { W = Ws0; Wt = Wts0; ksh = 8; e = (b - 512) * 256 + threadIdx.x; }
    else              { W = W1;  Wt = Wt1;  ksh = 8; e = (b - 768) * 256 + threadIdx.x; }
    int K = 1 << ksh;
    int n = e >> ksh;
    int k = e & (K - 1);
    Wt[e] = f2bf(W[((size_t)k << 8) + n]);
}

// ---------------------------------------------------------------------------
// MFMA GEMM: C[M x 256] = A[M x K] @ W[K x 256] + bias.  A is f32 (converted
// during staging). W given as Wt[n][k] bf16. BM=128, BN=256, BK=32.
// 512 threads = 8 waves (2x4), 64x64 per wave. Epilogue emits per-block
// column sum/sumsq partials (for BN).
// ---------------------------------------------------------------------------
template<typename OT>
__global__ __launch_bounds__(512) void gemm_mfma(
    const float* __restrict__ Af, const u16* __restrict__ Wt,
    const float* __restrict__ bias, OT* __restrict__ C,
    float* __restrict__ partial, int M, int K)
{
    __shared__ u16 As[128 * 40];
    __shared__ u16 Bs[256 * 40];
    const int t = threadIdx.x;
    const int bm = blockIdx.x * 128;
    const int lane = t & 63;
    const int wid = t >> 6;
    const int wr = wid >> 2;       // 0..1
    const int wc = wid & 3;        // 0..3

    const int arow = t >> 2;       // 0..127
    const int koff = (t & 3) * 8;  // 0,8,16,24

    f32x4 acc[4][4] = {};

    float4 ga0, ga1;
    ushort8 gb0, gb1;

    auto LOAD = [&](int k0) {
        const float* p = Af + (size_t)(bm + arow) * K + k0 + koff;
        ga0 = *(const float4*)p;
        ga1 = *(const float4*)(p + 4);
        const u16* q = Wt + (size_t)arow * K + k0 + koff;
        gb0 = *(const ushort8*)q;
        gb1 = *(const ushort8*)(q + (size_t)128 * K);
    };

    const int nk = K >> 5;
    LOAD(0);
    for (int it = 0; it < nk; ++it) {
        __syncthreads();   // previous iter's fragment reads complete
        {
            uint4 w;
            w.x = pack2(ga0.x, ga0.y);
            w.y = pack2(ga0.z, ga0.w);
            w.z = pack2(ga1.x, ga1.y);
            w.w = pack2(ga1.z, ga1.w);
            *(uint4*)&As[arow * 40 + koff] = w;
        }
        *(ushort8*)&Bs[arow * 40 + koff] = gb0;
        *(ushort8*)&Bs[(128 + arow) * 40 + koff] = gb1;
        __syncthreads();
        if (it + 1 < nk) LOAD((it + 1) << 5);   // next loads fly under MFMA

        const int kq = (lane >> 4) * 8;
        const int rr = lane & 15;
        short8 af[4];
#pragma unroll
        for (int mi = 0; mi < 4; ++mi)
            af[mi] = *(const short8*)&As[(wr * 64 + mi * 16 + rr) * 40 + kq];
#pragma unroll
        for (int ni = 0; ni < 4; ++ni) {
            short8 bf = *(const short8*)&Bs[(wc * 64 + ni * 16 + rr) * 40 + kq];
#pragma unroll
            for (int mi = 0; mi < 4; ++mi)
                acc[mi][ni] = __builtin_amdgcn_mfma_f32_16x16x32_bf16(
                    af[mi], bf, acc[mi][ni], 0, 0, 0);
        }
    }

    __syncthreads();   // fragment reads done everywhere; LDS reusable
    float* cs  = (float*)As;
    float* cs2 = ((float*)As) + 512;
    const int r4 = (lane >> 4) * 4;
    const int cc = lane & 15;
#pragma unroll
    for (int ni = 0; ni < 4; ++ni) {
        int col = wc * 64 + ni * 16 + cc;
        float bv = bias[col];
        float s = 0.f, s2 = 0.f;
#pragma unroll
        for (int mi = 0; mi < 4; ++mi) {
            size_t r0 = (size_t)bm + wr * 64 + mi * 16 + r4;
            f32x4 v = acc[mi][ni];
#pragma unroll
            for (int j = 0; j < 4; ++j) {
                float val = v[j] + bv;
                s += val;
                s2 = fmaf(val, val, s2);
                if constexpr (sizeof(OT) == 4)
                    C[(r0 + j) * 256 + col] = val;
                else
                    C[(r0 + j) * 256 + col] = f2bf(val);
            }
        }
        s  += __shfl_xor(s, 16);  s  += __shfl_xor(s, 32);
        s2 += __shfl_xor(s2, 16); s2 += __shfl_xor(s2, 32);
        if (lane < 16) { cs[wr * 256 + col] = s; cs2[wr * 256 + col] = s2; }
    }
    __syncthreads();
    if (t < 256) {
        partial[(size_t)blockIdx.x * 512 + t]       = cs[t] + cs[256 + t];
        partial[(size_t)blockIdx.x * 512 + 256 + t] = cs2[t] + cs2[256 + t];
    }
}

// ---------------------------------------------------------------------------
// Fused GEMM for layer 1: A-staging computes
//   x[row][k] = relu( (w0*y2[i0][k]+w1*y2[i1][k]+w2*y2[i2][k])*sf[k]
//                     + sk[row][k]*sx[k] + csh[k] )
// on the fly (csh = shift_f0 + shift_s0, folded by the finalize kernel).
// Then C = x @ W1 + b1, with column-stat partials. K = 256 fixed.
// ---------------------------------------------------------------------------
template<typename OT>
__global__ __launch_bounds__(512) void gemm_fused(
    const u16* __restrict__ skipb, const u16* __restrict__ y2,
    const float* __restrict__ dist, const int* __restrict__ idx,
    const float* __restrict__ ssf, const float* __restrict__ sss,
    const u16* __restrict__ Wt, const float* __restrict__ bias,
    OT* __restrict__ C, float* __restrict__ partial)
{
    const int K = 256;
    __shared__ u16 As[128 * 40];
    __shared__ u16 Bs[256 * 40];
    const int t = threadIdx.x;
    const int bm = blockIdx.x * 128;
    const int lane = t & 63;
    const int wid = t >> 6;
    const int wr = wid >> 2;
    const int wc = wid & 3;

    const int arow = t >> 2;       // 0..127
    const int koff = (t & 3) * 8;  // 0,8,16,24
    const int row = bm + arow;

    // per-row interpolation weights (4 threads/row redundant, one-time)
    float d0 = dist[row * 3 + 0], d1 = dist[row * 3 + 1], d2 = dist[row * 3 + 2];
    float r0 = 1.f / (d0 + 1e-8f), r1 = 1.f / (d1 + 1e-8f), r2 = 1.f / (d2 + 1e-8f);
    float inv = 1.f / (r0 + r1 + r2);
    const float w0 = r0 * inv, w1 = r1 * inv, w2 = r2 * inv;
    const size_t i0 = (size_t)idx[row * 3 + 0];
    const size_t i1 = (size_t)idx[row * 3 + 1];
    const size_t i2 = (size_t)idx[row * 3 + 2];

    f32x4 acc[4][4] = {};

    ushort8 sk8, a0, a1, a2, gb0, gb1;
    f32x8 sf, sx, csh;

    auto LOAD = [&](int k0) {
        const int kc = k0 + koff;
        sk8 = *(const ushort8*)(skipb + (size_t)row * 256 + kc);
        a0  = *(const ushort8*)(y2 + i0 * 256 + kc);
        a1  = *(const ushort8*)(y2 + i1 * 256 + kc);
        a2  = *(const ushort8*)(y2 + i2 * 256 + kc);
        sf  = *(const f32x8*)(ssf + kc);          // scale_f0
        sx  = *(const f32x8*)(sss + kc);          // scale_s0
        csh = *(const f32x8*)(sss + 256 + kc);    // shift_s0 + shift_f0 (folded)
        const u16* q = Wt + (size_t)arow * K + k0 + koff;
        gb0 = *(const ushort8*)q;
        gb1 = *(const ushort8*)(q + (size_t)128 * K);
    };

    const int nk = K >> 5;   // 8
    LOAD(0);
    for (int it = 0; it < nk; ++it) {
        __syncthreads();
        {
            float xs[8];
#pragma unroll
            for (int j = 0; j < 8; ++j) {
                float iv = w0 * toF((u16)a0[j]) + w1 * toF((u16)a1[j])
                         + w2 * toF((u16)a2[j]);
                float val = fmaf(iv, sf[j], fmaf(toF((u16)sk8[j]), sx[j], csh[j]));
                xs[j] = fmaxf(val, 0.f);
            }
            uint4 w;
            w.x = pack2(xs[0], xs[1]);
            w.y = pack2(xs[2], xs[3]);
            w.z = pack2(xs[4], xs[5]);
            w.w = pack2(xs[6], xs[7]);
            *(uint4*)&As[arow * 40 + koff] = w;
        }
        *(ushort8*)&Bs[arow * 40 + koff] = gb0;
        *(ushort8*)&Bs[(128 + arow) * 40 + koff] = gb1;
        __syncthreads();
        if (it + 1 < nk) LOAD((it + 1) << 5);

        const int kq = (lane >> 4) * 8;
        const int rr = lane & 15;
        short8 af[4];
#pragma unroll
        for (int mi = 0; mi < 4; ++mi)
            af[mi] = *(const short8*)&As[(wr * 64 + mi * 16 + rr) * 40 + kq];
#pragma unroll
        for (int ni = 0; ni < 4; ++ni) {
            short8 bf = *(const short8*)&Bs[(wc * 64 + ni * 16 + rr) * 40 + kq];
#pragma unroll
            for (int mi = 0; mi < 4; ++mi)
                acc[mi][ni] = __builtin_amdgcn_mfma_f32_16x16x32_bf16(
                    af[mi], bf, acc[mi][ni], 0, 0, 0);
        }
    }

    __syncthreads();
    float* cs  = (float*)As;
    float* cs2 = ((float*)As) + 512;
    const int r4 = (lane >> 4) * 4;
    const int cc = lane & 15;
#pragma unroll
    for (int ni = 0; ni < 4; ++ni) {
        int col = wc * 64 + ni * 16 + cc;
        float bv = bias[col];
        float s = 0.f, s2 = 0.f;
#pragma unroll
        for (int mi = 0; mi < 4; ++mi) {
            size_t r0 = (size_t)bm + wr * 64 + mi * 16 + r4;
            f32x4 v = acc[mi][ni];
#pragma unroll
            for (int j = 0; j < 4; ++j) {
                float val = v[j] + bv;
                s += val;
                s2 = fmaf(val, val, s2);
                if constexpr (sizeof(OT) == 4)
                    C[(r0 + j) * 256 + col] = val;
                else
                    C[(r0 + j) * 256 + col] = f2bf(val);
            }
        }
        s  += __shfl_xor(s, 16);  s  += __shfl_xor(s, 32);
        s2 += __shfl_xor(s2, 16); s2 += __shfl_xor(s2, 32);
        if (lane < 16) { cs[wr * 256 + col] = s; cs2[wr * 256 + col] = s2; }
    }
    __syncthreads();
    if (t < 256) {
        partial[(size_t)blockIdx.x * 512 + t]       = cs[t] + cs[256 + t];
        partial[(size_t)blockIdx.x * 512 + 256 + t] = cs2[t] + cs2[256 + t];
    }
}

// ---------------------------------------------------------------------------
// Stats finalize: one block per column. Reduce nb block-partials, emit
// scale/shift. If fold!=null, shift += fold[256+c] (shift folding).
// ---------------------------------------------------------------------------
__global__ __launch_bounds__(256) void colstats_final_par(
    const float* __restrict__ partial, int nb, float invR,
    const float* __restrict__ g, const float* __restrict__ beta,
    const float* __restrict__ fold, float* __restrict__ ss)
{
    int c = blockIdx.x;
    int t = threadIdx.x;
    float s = 0.f, s2 = 0.f;
    for (int b = t; b < nb; b += 256) {
        s  += partial[(size_t)b * 512 + c];
        s2 += partial[(size_t)b * 512 + 256 + c];
    }
#pragma unroll
    for (int o = 32; o > 0; o >>= 1) {
        s += __shfl_xor(s, o);
        s2 += __shfl_xor(s2, o);
    }
    __shared__ float rs[4], rs2[4];
    if ((t & 63) == 0) { rs[t >> 6] = s; rs2[t >> 6] = s2; }
    __syncthreads();
    if (t == 0) {
        float S  = rs[0] + rs[1] + rs[2] + rs[3];
        float S2 = rs2[0] + rs2[1] + rs2[2] + rs2[3];
        float m = S * invR;
        float var = fmaf(-m, m, S2 * invR);
        float scale = g[c] * rsqrtf(var + 1e-5f);
        float shift = fmaf(-m, scale, beta[c]);
        if (fold) shift += fold[256 + c];
        ss[c] = scale;
        ss[256 + c] = shift;
    }
}

// ---------------------------------------------------------------------------
// out(f32) = relu(y3(bf16) * scale + shift)
// ---------------------------------------------------------------------------
__global__ __launch_bounds__(256) void bn_relu_cvt(
    const u16* __restrict__ y3, float* __restrict__ out,
    const float* __restrict__ ss)
{
    size_t e = ((size_t)blockIdx.x * 256 + threadIdx.x) * 8;
    int kc = (int)(e & 255);
    ushort8 v = *(const ushort8*)(y3 + e);
    f32x8 sc = *(const f32x8*)(ss + kc);
    f32x8 sh = *(const f32x8*)(ss + 256 + kc);
    float4 o0, o1;
    o0.x = fmaxf(fmaf(toF((u16)v[0]), sc[0], sh[0]), 0.f);
    o0.y = fmaxf(fmaf(toF((u16)v[1]), sc[1], sh[1]), 0.f);
    o0.z = fmaxf(fmaf(toF((u16)v[2]), sc[2], sh[2]), 0.f);
    o0.w = fmaxf(fmaf(toF((u16)v[3]), sc[3], sh[3]), 0.f);
    o1.x = fmaxf(fmaf(toF((u16)v[4]), sc[4], sh[4]), 0.f);
    o1.y = fmaxf(fmaf(toF((u16)v[5]), sc[5], sh[5]), 0.f);
    o1.z = fmaxf(fmaf(toF((u16)v[6]), sc[6], sh[6]), 0.f);
    o1.w = fmaxf(fmaf(toF((u16)v[7]), sc[7], sh[7]), 0.f);
    *(float4*)(out + e) = o0;
    *(float4*)(out + e + 4) = o1;
}

// ---------------------------------------------------------------------------
// out = relu(out * scale + shift), in place (fallback when ws too small)
// ---------------------------------------------------------------------------
__global__ __launch_bounds__(256) void bn_relu_inplace(
    float* __restrict__ out, const float* __restrict__ ss)
{
    size_t i4 = (size_t)blockIdx.x * 256 + threadIdx.x;
    int c4 = (int)(i4 & 63);
    float4 v = reinterpret_cast<float4*>(out)[i4];
    float4 sc = reinterpret_cast<const float4*>(ss)[c4];
    float4 sh = reinterpret_cast<const float4*>(ss + 256)[c4];
    v.x = fmaxf(fmaf(v.x, sc.x, sh.x), 0.f);
    v.y = fmaxf(fmaf(v.y, sc.y, sh.y), 0.f);
    v.z = fmaxf(fmaf(v.z, sc.z, sh.z), 0.f);
    v.w = fmaxf(fmaf(v.w, sc.w, sh.w), 0.f);
    reinterpret_cast<float4*>(out)[i4] = v;
}

// ---------------------------------------------------------------------------
extern "C" void kernel_launch(void* const* d_in, const int* in_sizes, int n_in,
                              void* d_out, int out_size, void* d_ws, size_t ws_size,
                              hipStream_t stream) {
    const float* points1 = (const float*)d_in[0];
    const float* points2 = (const float*)d_in[1];
    const float* dist    = (const float*)d_in[2];
    const int*   idx     = (const int*)d_in[3];
    const float* Wf0     = (const float*)d_in[4];
    const float* bf0     = (const float*)d_in[5];
    const float* gf0     = (const float*)d_in[6];
    const float* betaf0  = (const float*)d_in[7];
    const float* Ws0     = (const float*)d_in[8];
    const float* bs0     = (const float*)d_in[9];
    const float* gs0     = (const float*)d_in[10];
    const float* betas0  = (const float*)d_in[11];
    const float* W1      = (const float*)d_in[12];
    const float* b1      = (const float*)d_in[13];
    const float* g1      = (const float*)d_in[14];
    const float* beta1   = (const float*)d_in[15];

    u16* ws = (u16*)d_ws;
    size_t off = 0;
    u16* y2   = ws + off;  off += (size_t)CN2 * 256;   // 32MB
    u16* xbuf = ws + off;  off += (size_t)CN1 * 256;   // 128MB
    u16* Wtf0 = ws + off;  off += 512 * 256;
    u16* Wts0 = ws + off;  off += 256 * 256;
    u16* Wt1  = ws + off;  off += 256 * 256;
    float* partial = (float*)(ws + off); off += (size_t)2048 * 512 * 2;  // 4MB
    float* ss_f0 = (float*)(ws + off); off += 1024;
    float* ss_s0 = (float*)(ws + off); off += 1024;
    float* ss_1  = (float*)(ws + off); off += 1024;
    u16* y3 = ws + off;
    const size_t NEED = (off + (size_t)CN1 * 256) * 2;   // bytes incl. bf16 y3
    const bool fused_y3 = (ws_size >= NEED);
    float* out = (float*)d_out;

    // weight transposes (f32 -> bf16, [K][256] -> [256][K]) in one launch
    transpose_all<<<1024, 256, 0, stream>>>(Wf0, Ws0, W1, Wtf0, Wts0, Wt1);

    // 1) y2 = points2 @ Wf0 + bf0   [N2 x 256] bf16, + col partials
    gemm_mfma<u16><<<CN2 / 128, 512, 0, stream>>>(
        points2, Wtf0, bf0, y2, partial, CN2, CPREV);
    colstats_final_par<<<256, 256, 0, stream>>>(partial, CN2 / 128, 1.0f / CN2,
                                                gf0, betaf0, nullptr, ss_f0);
    // 2) skip_pre = points1 @ Ws0 + bs0   [N1 x 256] bf16, + col partials
    gemm_mfma<u16><<<CN1 / 128, 512, 0, stream>>>(
        points1, Wts0, bs0, xbuf, partial, CN1, CSKIP);
    // fold f0 shift into s0 shift (interp identity: sum w = 1)
    colstats_final_par<<<256, 256, 0, stream>>>(partial, CN1 / 128, 1.0f / CN1,
                                                gs0, betas0, ss_f0, ss_s0);
    // 3) y3 = relu(interp+skip) @ W1 + b1 (interp fused into staging)
    if (fused_y3) {
        gemm_fused<u16><<<CN1 / 128, 512, 0, stream>>>(
            xbuf, y2, dist, idx, ss_f0, ss_s0, Wt1, b1, y3, partial);
    } else {
        gemm_fused<float><<<CN1 / 128, 512, 0, stream>>>(
            xbuf, y2, dist, idx, ss_f0, ss_s0, Wt1, b1, out, partial);
    }
    colstats_final_par<<<256, 256, 0, stream>>>(partial, CN1 / 128, 1.0f / CN1,
                                                g1, beta1, nullptr, ss_1);
    // 4) out = relu(bn(y3))
    if (fused_y3) {
        bn_relu_cvt<<<32768, 256, 0, stream>>>(y3, out, ss_1);
    } else {
        bn_relu_inplace<<<CN1 / 4, 256, 0, stream>>>(out, ss_1);
    }
}